// Round 8
// baseline (113.700 us; speedup 1.0000x reference)
//
#include <hip/hip_runtime.h>

// FeatureWithRelativePosition: fused pairwise-dist -> Linear(4096->64) -> LN -> SiLU
// BS=4, N=4096, FEAT=64. fp32 in/out, bf16 MFMA inner product, fp32 accumulate.
//
// R8: kill the per-iteration load latency (R4/R5/R7 all plateaued ~33-40us on
//     it): (1) positions staged to LDS ONCE at start (48KiB, one barrier) ->
//     in-loop pos access is ds_read_b128 (~120cyc, conflict-free broadcast);
//     (2) W fragments explicitly prefetched one iteration ahead in registers
//     (rotation, unroll 1) so their ~300cyc L2 latency hides under the ~420cyc
//     distance math. No barriers in the K-loop. LDS merge reuses the pos LDS.

typedef float f32x4 __attribute__((ext_vector_type(4)));
typedef __bf16 bf16x8 __attribute__((ext_vector_type(8)));

union BF8 { bf16x8 v; uint4 u; };

#define N_PTS 4096
#define FEATD 64

// ---- prep: blocks 0..127 convert W fp32 -> bf16 granule-major Wbt[512][64][8];
//      blocks 128..143 transpose pos -> Pt[coord][batch][4096] (SoA) ----
__global__ void prep_kernel(const float* __restrict__ W,
                            const float* __restrict__ pos,
                            unsigned short* __restrict__ Wbt,
                            float* __restrict__ Pt) {
  int b = blockIdx.x, t = threadIdx.x;  // 256 threads
  if (b < 128) {
    int gid = b * 256 + t;              // 32768 = 64 f * 512 G
    int f = gid >> 9, m8 = gid & 511;
    const float4* src = (const float4*)(W + (size_t)f * N_PTS + m8 * 8);
    float4 a = src[0], bb = src[1];
    BF8 o;
    o.v[0] = (__bf16)a.x;  o.v[1] = (__bf16)a.y;  o.v[2] = (__bf16)a.z;  o.v[3] = (__bf16)a.w;
    o.v[4] = (__bf16)bb.x; o.v[5] = (__bf16)bb.y; o.v[6] = (__bf16)bb.z; o.v[7] = (__bf16)bb.w;
    ((uint4*)Wbt)[(size_t)m8 * 64 + f] = o.u;
  } else {
    int bb = b - 128;          // 0..15
    int batch = bb >> 2, qtr = bb & 3;
    const float4* p4 = (const float4*)(pos + ((size_t)batch * N_PTS + qtr * 1024) * 3);
    float4 f0 = p4[t * 3 + 0], f1 = p4[t * 3 + 1], f2 = p4[t * 3 + 2];
    float4* Px = (float4*)(Pt + (size_t)(0 * 4 + batch) * N_PTS) + qtr * 256;
    float4* Py = (float4*)(Pt + (size_t)(1 * 4 + batch) * N_PTS) + qtr * 256;
    float4* Pz = (float4*)(Pt + (size_t)(2 * 4 + batch) * N_PTS) + qtr * 256;
    Px[t] = make_float4(f0.x, f0.w, f1.z, f2.y);
    Py[t] = make_float4(f0.y, f1.x, f1.w, f2.z);
    Pz[t] = make_float4(f0.z, f1.y, f2.x, f2.w);
  }
}

// ---- shared merge + epilogue (mbuf must hold 4*512 f32x4 = 32 KiB) ----
__device__ __forceinline__ void merge_and_epilogue(
    f32x4 (&acc)[2][4], f32x4* mbuf, int wave, int lane, int fx, int q,
    int batch, int rb, const float* bias, const float* gamma,
    const float* beta, float* out) {
  auto wr = [&](int rg) {
#pragma unroll
    for (int a = 0; a < 2; ++a)
#pragma unroll
      for (int t = 0; t < 4; ++t)
        mbuf[rg * 512 + (a * 4 + t) * 64 + lane] = acc[a][t];
  };
  auto rd = [&](int rg) {
#pragma unroll
    for (int a = 0; a < 2; ++a)
#pragma unroll
      for (int t = 0; t < 4; ++t)
        acc[a][t] += mbuf[rg * 512 + (a * 4 + t) * 64 + lane];
  };
  if (wave >= 4) wr(wave - 4);
  __syncthreads();
  if (wave < 4) rd(wave);
  __syncthreads();
  if (wave == 2 || wave == 3) wr(wave - 2);
  __syncthreads();
  if (wave < 2) rd(wave);
  __syncthreads();
  if (wave == 1) wr(0);
  __syncthreads();

  if (wave == 0) {
    rd(0);
    float bb[4], gg[4], be[4];
#pragma unroll
    for (int t = 0; t < 4; ++t) {
      bb[t] = bias[t * 16 + fx];
      gg[t] = gamma[t * 16 + fx];
      be[t] = beta[t * 16 + fx];
    }
    float* outB = out + ((size_t)batch * N_PTS + rb) * FEATD;
#pragma unroll
    for (int a = 0; a < 2; ++a) {
#pragma unroll
      for (int r = 0; r < 4; ++r) {
        float x[4], d[4];
#pragma unroll
        for (int t = 0; t < 4; ++t) x[t] = acc[a][t][r] + bb[t];
        float s = x[0] + x[1] + x[2] + x[3];
        s += __shfl_xor(s, 1); s += __shfl_xor(s, 2);
        s += __shfl_xor(s, 4); s += __shfl_xor(s, 8);
        float mu = s * (1.f / 64.f);
        float v = 0.f;
#pragma unroll
        for (int t = 0; t < 4; ++t) { d[t] = x[t] - mu; v += d[t] * d[t]; }
        v += __shfl_xor(v, 1); v += __shfl_xor(v, 2);
        v += __shfl_xor(v, 4); v += __shfl_xor(v, 8);
        float rstd = __builtin_amdgcn_rsqf(v * (1.f / 64.f) + 1e-5f);
        float* orow = outB + (a * 16 + q * 4 + r) * FEATD;
#pragma unroll
        for (int t = 0; t < 4; ++t) {
          float xn = d[t] * rstd * gg[t] + be[t];
          float y = xn * (1.f / (1.f + __expf(-xn)));  // SiLU
          orow[t * 16 + fx] = y;
        }
      }
    }
  }
}

// grid = 512 (batch = bid>>7, rowblk = (bid&127)*32), block = 512 thr (8 waves).
// wave = K-slice; every wave covers all 32 rows (2 rowtiles x 4 ftiles).
__global__ __launch_bounds__(512, 4) void frp_kernel(
    const float* __restrict__ bias, const float* __restrict__ gamma,
    const float* __restrict__ beta, const unsigned short* __restrict__ Wbt,
    const float* __restrict__ Pt, float* __restrict__ out) {
  __shared__ __align__(16) float Pl[3 * N_PTS];   // 48 KiB pos SoA; reused as merge buf

  const int tid = threadIdx.x;
  const int lane = tid & 63;
  const int wave = tid >> 6;       // 0..7 = K-slice
  const int fx = lane & 15;
  const int q = lane >> 4;

  const int batch = blockIdx.x >> 7;
  const int rb = (blockIdx.x & 127) * 32;

  // ---- stage all positions into LDS (once; coalesced; 6 float4/thread) ----
#pragma unroll
  for (int cc = 0; cc < 3; ++cc) {
    const float4* s = (const float4*)(Pt + (size_t)(cc * 4 + batch) * N_PTS);
    float4* d = (float4*)(Pl + cc * N_PTS);
    d[tid] = s[tid];
    d[tid + 512] = s[tid + 512];
  }
  __syncthreads();   // the only barrier before the merge

  const float* PxL = Pl;
  const float* PyL = Pl + N_PTS;
  const float* PzL = Pl + 2 * N_PTS;

  f32x4 acc[2][4];
#pragma unroll
  for (int a = 0; a < 2; ++a)
#pragma unroll
    for (int t = 0; t < 4; ++t) acc[a][t] = (f32x4){0.f, 0.f, 0.f, 0.f};

  // A-row positions (2 rowtiles): rows rb + a*16 + fx  (LDS broadcast)
  const int n0 = rb + fx;
  const float px0 = PxL[n0],      py0 = PyL[n0],      pz0 = PzL[n0];
  const float px1 = PxL[n0 + 16], py1 = PyL[n0 + 16], pz1 = PzL[n0 + 16];

  const int G0 = wave * 4 + q;                       // granule within chunk
  const uint4* wgp = (const uint4*)Wbt + (size_t)G0 * 64 + fx;

  // prefetch W fragments for c=0
  uint4 w0n = wgp[0], w1n = wgp[16], w2n = wgp[32], w3n = wgp[48];

#pragma unroll 1
  for (int c = 0; c < 16; ++c) {
    uint4 w0 = w0n, w1 = w1n, w2 = w2n, w3 = w3n;
    if (c < 15) {   // issue next iteration's W loads BEFORE this iter's math
      const uint4* wn = wgp + (size_t)(c + 1) * 2048;
      w0n = wn[0]; w1n = wn[16]; w2n = wn[32]; w3n = wn[48];
    }

    const int m4 = (c * 32 + G0) * 2;               // f32x4 index into LDS SoA
    f32x4 xa = ((const f32x4*)PxL)[m4], xb = ((const f32x4*)PxL)[m4 + 1];
    f32x4 ya = ((const f32x4*)PyL)[m4], yb = ((const f32x4*)PyL)[m4 + 1];
    f32x4 za = ((const f32x4*)PzL)[m4], zb = ((const f32x4*)PzL)[m4 + 1];

    bf16x8 af0, af1;
    {
      f32x4 dx = xa - px0, dy = ya - py0, dz = za - pz0;
      f32x4 sq = dx * dx + dy * dy + dz * dz;
#pragma unroll
      for (int j = 0; j < 4; ++j) af0[j] = (__bf16)__builtin_amdgcn_sqrtf(sq[j]);
      dx = xb - px0; dy = yb - py0; dz = zb - pz0;
      sq = dx * dx + dy * dy + dz * dz;
#pragma unroll
      for (int j = 0; j < 4; ++j) af0[4 + j] = (__bf16)__builtin_amdgcn_sqrtf(sq[j]);
      dx = xa - px1; dy = ya - py1; dz = za - pz1;
      sq = dx * dx + dy * dy + dz * dz;
#pragma unroll
      for (int j = 0; j < 4; ++j) af1[j] = (__bf16)__builtin_amdgcn_sqrtf(sq[j]);
      dx = xb - px1; dy = yb - py1; dz = zb - pz1;
      sq = dx * dx + dy * dy + dz * dz;
#pragma unroll
      for (int j = 0; j < 4; ++j) af1[4 + j] = (__bf16)__builtin_amdgcn_sqrtf(sq[j]);
    }
    BF8 b0, b1, b2, b3;
    b0.u = w0; b1.u = w1; b2.u = w2; b3.u = w3;
    acc[0][0] = __builtin_amdgcn_mfma_f32_16x16x32_bf16(af0, b0.v, acc[0][0], 0, 0, 0);
    acc[1][0] = __builtin_amdgcn_mfma_f32_16x16x32_bf16(af1, b0.v, acc[1][0], 0, 0, 0);
    acc[0][1] = __builtin_amdgcn_mfma_f32_16x16x32_bf16(af0, b1.v, acc[0][1], 0, 0, 0);
    acc[1][1] = __builtin_amdgcn_mfma_f32_16x16x32_bf16(af1, b1.v, acc[1][1], 0, 0, 0);
    acc[0][2] = __builtin_amdgcn_mfma_f32_16x16x32_bf16(af0, b2.v, acc[0][2], 0, 0, 0);
    acc[1][2] = __builtin_amdgcn_mfma_f32_16x16x32_bf16(af1, b2.v, acc[1][2], 0, 0, 0);
    acc[0][3] = __builtin_amdgcn_mfma_f32_16x16x32_bf16(af0, b3.v, acc[0][3], 0, 0, 0);
    acc[1][3] = __builtin_amdgcn_mfma_f32_16x16x32_bf16(af1, b3.v, acc[1][3], 0, 0, 0);
  }

  __syncthreads();   // everyone done reading Pl; reuse it as the merge buffer
  merge_and_epilogue(acc, (f32x4*)Pl, wave, lane, fx, q, batch, rb,
                     bias, gamma, beta, out);
}

// ---- fallback (only if ws too small; correctness-only) ----
__global__ __launch_bounds__(512) void frp_fallback_kernel(
    const float* __restrict__ pos, const float* __restrict__ W,
    const float* __restrict__ bias, const float* __restrict__ gamma,
    const float* __restrict__ beta, float* __restrict__ out) {
  __shared__ f32x4 mbuf[4 * 512];
  const int tid = threadIdx.x;
  const int lane = tid & 63;
  const int wave = tid >> 6;
  const int fx = lane & 15;
  const int q = lane >> 4;
  const int batch = blockIdx.x >> 7;
  const int rb = (blockIdx.x & 127) * 32;
  const float* posB = pos + (size_t)batch * N_PTS * 3;

  f32x4 acc[2][4];
#pragma unroll
  for (int a = 0; a < 2; ++a)
#pragma unroll
    for (int t = 0; t < 4; ++t) acc[a][t] = (f32x4){0.f, 0.f, 0.f, 0.f};

  const int G0 = wave * 4 + q;
  const int n0 = rb + fx;
  const float px0 = posB[n0 * 3], py0 = posB[n0 * 3 + 1], pz0 = posB[n0 * 3 + 2];
  const float px1 = posB[(n0 + 16) * 3], py1 = posB[(n0 + 16) * 3 + 1],
              pz1 = posB[(n0 + 16) * 3 + 2];

  for (int c = 0; c < 16; ++c) {
    const int G = c * 32 + G0;
    bf16x8 af0, af1;
#pragma unroll
    for (int j = 0; j < 8; ++j) {
      const float* pk = posB + ((size_t)G * 8 + j) * 3;
      float kx = pk[0], ky = pk[1], kz = pk[2];
      float dx = kx - px0, dy = ky - py0, dz = kz - pz0;
      af0[j] = (__bf16)__builtin_amdgcn_sqrtf(dx * dx + dy * dy + dz * dz);
      dx = kx - px1; dy = ky - py1; dz = kz - pz1;
      af1[j] = (__bf16)__builtin_amdgcn_sqrtf(dx * dx + dy * dy + dz * dz);
    }
#pragma unroll
    for (int t = 0; t < 4; ++t) {
      const float* wr = W + (size_t)(t * 16 + fx) * N_PTS + G * 8;
      BF8 bw;
#pragma unroll
      for (int j = 0; j < 8; ++j) bw.v[j] = (__bf16)wr[j];
      acc[0][t] = __builtin_amdgcn_mfma_f32_16x16x32_bf16(af0, bw.v, acc[0][t], 0, 0, 0);
      acc[1][t] = __builtin_amdgcn_mfma_f32_16x16x32_bf16(af1, bw.v, acc[1][t], 0, 0, 0);
    }
  }
  merge_and_epilogue(acc, mbuf, wave, lane, fx, q, batch, rb,
                     bias, gamma, beta, out);
}

extern "C" void kernel_launch(void* const* d_in, const int* in_sizes, int n_in,
                              void* d_out, int out_size, void* d_ws, size_t ws_size,
                              hipStream_t stream) {
  const float* pos   = (const float*)d_in[0];  // (4,4096,3)
  const float* W     = (const float*)d_in[1];  // (64,4096)
  const float* bias  = (const float*)d_in[2];  // (64,)
  const float* gamma = (const float*)d_in[3];  // (64,)
  const float* beta  = (const float*)d_in[4];  // (64,)
  float* out = (float*)d_out;                  // (4,4096,64)

  const size_t wb_bytes = (size_t)FEATD * N_PTS * sizeof(unsigned short);  // 512 KiB
  const size_t pt_bytes = (size_t)3 * 4 * N_PTS * sizeof(float);           // 192 KiB
  int use_ws = (d_ws != nullptr && ws_size >= wb_bytes + pt_bytes);

  if (use_ws) {
    unsigned short* Wbt = (unsigned short*)d_ws;
    float* Pt = (float*)((char*)d_ws + wb_bytes);
    prep_kernel<<<dim3(144), dim3(256), 0, stream>>>(W, pos, Wbt, Pt);
    frp_kernel<<<dim3(512), dim3(512), 0, stream>>>(bias, gamma, beta, Wbt, Pt, out);
  } else {
    frp_fallback_kernel<<<dim3(512), dim3(512), 0, stream>>>(pos, W, bias, gamma,
                                                             beta, out);
  }
}

// Round 9
// 94.185 us; speedup vs baseline: 1.2072x; 1.2072x over previous
//
#include <hip/hip_runtime.h>

// FeatureWithRelativePosition: fused pairwise-dist -> Linear(4096->64) -> LN -> SiLU
// BS=4, N=4096, FEAT=64. fp32 in/out, bf16 MFMA inner product, fp32 accumulate.
//
// R9: R8 structure (pos in LDS once, W register-prefetched 1 iter ahead, no
//     K-loop barriers) with the register allocator pinned:
//     amdgpu_waves_per_eu(2,4). R8's (512,4) bound let the compiler squeeze
//     to 64 VGPRs for 8 waves/EU and spill the prefetch regs to scratch
//     (WRITE_SIZE 14MB vs 4MB of real output). Max=4 waves/EU removes the
//     incentive to allocate below ~128.

typedef float f32x4 __attribute__((ext_vector_type(4)));
typedef __bf16 bf16x8 __attribute__((ext_vector_type(8)));

union BF8 { bf16x8 v; uint4 u; };

#define N_PTS 4096
#define FEATD 64

// ---- prep: blocks 0..127 convert W fp32 -> bf16 granule-major Wbt[512][64][8];
//      blocks 128..143 transpose pos -> Pt[coord][batch][4096] (SoA) ----
__global__ void prep_kernel(const float* __restrict__ W,
                            const float* __restrict__ pos,
                            unsigned short* __restrict__ Wbt,
                            float* __restrict__ Pt) {
  int b = blockIdx.x, t = threadIdx.x;  // 256 threads
  if (b < 128) {
    int gid = b * 256 + t;              // 32768 = 64 f * 512 G
    int f = gid >> 9, m8 = gid & 511;
    const float4* src = (const float4*)(W + (size_t)f * N_PTS + m8 * 8);
    float4 a = src[0], bb = src[1];
    BF8 o;
    o.v[0] = (__bf16)a.x;  o.v[1] = (__bf16)a.y;  o.v[2] = (__bf16)a.z;  o.v[3] = (__bf16)a.w;
    o.v[4] = (__bf16)bb.x; o.v[5] = (__bf16)bb.y; o.v[6] = (__bf16)bb.z; o.v[7] = (__bf16)bb.w;
    ((uint4*)Wbt)[(size_t)m8 * 64 + f] = o.u;
  } else {
    int bb = b - 128;          // 0..15
    int batch = bb >> 2, qtr = bb & 3;
    const float4* p4 = (const float4*)(pos + ((size_t)batch * N_PTS + qtr * 1024) * 3);
    float4 f0 = p4[t * 3 + 0], f1 = p4[t * 3 + 1], f2 = p4[t * 3 + 2];
    float4* Px = (float4*)(Pt + (size_t)(0 * 4 + batch) * N_PTS) + qtr * 256;
    float4* Py = (float4*)(Pt + (size_t)(1 * 4 + batch) * N_PTS) + qtr * 256;
    float4* Pz = (float4*)(Pt + (size_t)(2 * 4 + batch) * N_PTS) + qtr * 256;
    Px[t] = make_float4(f0.x, f0.w, f1.z, f2.y);
    Py[t] = make_float4(f0.y, f1.x, f1.w, f2.z);
    Pz[t] = make_float4(f0.z, f1.y, f2.x, f2.w);
  }
}

// ---- shared merge + epilogue (mbuf must hold 4*512 f32x4 = 32 KiB) ----
__device__ __forceinline__ void merge_and_epilogue(
    f32x4 (&acc)[2][4], f32x4* mbuf, int wave, int lane, int fx, int q,
    int batch, int rb, const float* bias, const float* gamma,
    const float* beta, float* out) {
  auto wr = [&](int rg) {
#pragma unroll
    for (int a = 0; a < 2; ++a)
#pragma unroll
      for (int t = 0; t < 4; ++t)
        mbuf[rg * 512 + (a * 4 + t) * 64 + lane] = acc[a][t];
  };
  auto rd = [&](int rg) {
#pragma unroll
    for (int a = 0; a < 2; ++a)
#pragma unroll
      for (int t = 0; t < 4; ++t)
        acc[a][t] += mbuf[rg * 512 + (a * 4 + t) * 64 + lane];
  };
  if (wave >= 4) wr(wave - 4);
  __syncthreads();
  if (wave < 4) rd(wave);
  __syncthreads();
  if (wave == 2 || wave == 3) wr(wave - 2);
  __syncthreads();
  if (wave < 2) rd(wave);
  __syncthreads();
  if (wave == 1) wr(0);
  __syncthreads();

  if (wave == 0) {
    rd(0);
    float bb[4], gg[4], be[4];
#pragma unroll
    for (int t = 0; t < 4; ++t) {
      bb[t] = bias[t * 16 + fx];
      gg[t] = gamma[t * 16 + fx];
      be[t] = beta[t * 16 + fx];
    }
    float* outB = out + ((size_t)batch * N_PTS + rb) * FEATD;
#pragma unroll
    for (int a = 0; a < 2; ++a) {
#pragma unroll
      for (int r = 0; r < 4; ++r) {
        float x[4], d[4];
#pragma unroll
        for (int t = 0; t < 4; ++t) x[t] = acc[a][t][r] + bb[t];
        float s = x[0] + x[1] + x[2] + x[3];
        s += __shfl_xor(s, 1); s += __shfl_xor(s, 2);
        s += __shfl_xor(s, 4); s += __shfl_xor(s, 8);
        float mu = s * (1.f / 64.f);
        float v = 0.f;
#pragma unroll
        for (int t = 0; t < 4; ++t) { d[t] = x[t] - mu; v += d[t] * d[t]; }
        v += __shfl_xor(v, 1); v += __shfl_xor(v, 2);
        v += __shfl_xor(v, 4); v += __shfl_xor(v, 8);
        float rstd = __builtin_amdgcn_rsqf(v * (1.f / 64.f) + 1e-5f);
        float* orow = outB + (a * 16 + q * 4 + r) * FEATD;
#pragma unroll
        for (int t = 0; t < 4; ++t) {
          float xn = d[t] * rstd * gg[t] + be[t];
          float y = xn * (1.f / (1.f + __expf(-xn)));  // SiLU
          orow[t * 16 + fx] = y;
        }
      }
    }
  }
}

// grid = 512 (batch = bid>>7, rowblk = (bid&127)*32), block = 512 thr (8 waves).
// wave = K-slice; every wave covers all 32 rows (2 rowtiles x 4 ftiles).
__global__ __launch_bounds__(512)
__attribute__((amdgpu_waves_per_eu(2, 4)))
void frp_kernel(
    const float* __restrict__ bias, const float* __restrict__ gamma,
    const float* __restrict__ beta, const unsigned short* __restrict__ Wbt,
    const float* __restrict__ Pt, float* __restrict__ out) {
  __shared__ __align__(16) float Pl[3 * N_PTS];   // 48 KiB pos SoA; reused as merge buf

  const int tid = threadIdx.x;
  const int lane = tid & 63;
  const int wave = tid >> 6;       // 0..7 = K-slice
  const int fx = lane & 15;
  const int q = lane >> 4;

  const int batch = blockIdx.x >> 7;
  const int rb = (blockIdx.x & 127) * 32;

  // ---- stage all positions into LDS (once; coalesced; 6 float4/thread) ----
#pragma unroll
  for (int cc = 0; cc < 3; ++cc) {
    const float4* s = (const float4*)(Pt + (size_t)(cc * 4 + batch) * N_PTS);
    float4* d = (float4*)(Pl + cc * N_PTS);
    d[tid] = s[tid];
    d[tid + 512] = s[tid + 512];
  }
  __syncthreads();   // the only barrier before the merge

  const float* PxL = Pl;
  const float* PyL = Pl + N_PTS;
  const float* PzL = Pl + 2 * N_PTS;

  f32x4 acc[2][4];
#pragma unroll
  for (int a = 0; a < 2; ++a)
#pragma unroll
    for (int t = 0; t < 4; ++t) acc[a][t] = (f32x4){0.f, 0.f, 0.f, 0.f};

  // A-row positions (2 rowtiles): rows rb + a*16 + fx  (LDS broadcast)
  const int n0 = rb + fx;
  const float px0 = PxL[n0],      py0 = PyL[n0],      pz0 = PzL[n0];
  const float px1 = PxL[n0 + 16], py1 = PyL[n0 + 16], pz1 = PzL[n0 + 16];

  const int G0 = wave * 4 + q;                       // granule within chunk
  const uint4* wgp = (const uint4*)Wbt + (size_t)G0 * 64 + fx;

  // prefetch W fragments for c=0
  uint4 w0n = wgp[0], w1n = wgp[16], w2n = wgp[32], w3n = wgp[48];

#pragma unroll 1
  for (int c = 0; c < 16; ++c) {
    uint4 w0 = w0n, w1 = w1n, w2 = w2n, w3 = w3n;
    {  // issue next iteration's W loads BEFORE this iter's math (clamped, no branch)
      const uint4* wn = wgp + (size_t)((c + 1) & 15) * 2048;
      w0n = wn[0]; w1n = wn[16]; w2n = wn[32]; w3n = wn[48];
    }

    const int m4 = (c * 32 + G0) * 2;               // f32x4 index into LDS SoA
    f32x4 xa = ((const f32x4*)PxL)[m4], xb = ((const f32x4*)PxL)[m4 + 1];
    f32x4 ya = ((const f32x4*)PyL)[m4], yb = ((const f32x4*)PyL)[m4 + 1];
    f32x4 za = ((const f32x4*)PzL)[m4], zb = ((const f32x4*)PzL)[m4 + 1];

    bf16x8 af0, af1;
    {
      f32x4 dx = xa - px0, dy = ya - py0, dz = za - pz0;
      f32x4 sq = dx * dx + dy * dy + dz * dz;
#pragma unroll
      for (int j = 0; j < 4; ++j) af0[j] = (__bf16)__builtin_amdgcn_sqrtf(sq[j]);
      dx = xb - px0; dy = yb - py0; dz = zb - pz0;
      sq = dx * dx + dy * dy + dz * dz;
#pragma unroll
      for (int j = 0; j < 4; ++j) af0[4 + j] = (__bf16)__builtin_amdgcn_sqrtf(sq[j]);
      dx = xa - px1; dy = ya - py1; dz = za - pz1;
      sq = dx * dx + dy * dy + dz * dz;
#pragma unroll
      for (int j = 0; j < 4; ++j) af1[j] = (__bf16)__builtin_amdgcn_sqrtf(sq[j]);
      dx = xb - px1; dy = yb - py1; dz = zb - pz1;
      sq = dx * dx + dy * dy + dz * dz;
#pragma unroll
      for (int j = 0; j < 4; ++j) af1[4 + j] = (__bf16)__builtin_amdgcn_sqrtf(sq[j]);
    }
    BF8 b0, b1, b2, b3;
    b0.u = w0; b1.u = w1; b2.u = w2; b3.u = w3;
    acc[0][0] = __builtin_amdgcn_mfma_f32_16x16x32_bf16(af0, b0.v, acc[0][0], 0, 0, 0);
    acc[1][0] = __builtin_amdgcn_mfma_f32_16x16x32_bf16(af1, b0.v, acc[1][0], 0, 0, 0);
    acc[0][1] = __builtin_amdgcn_mfma_f32_16x16x32_bf16(af0, b1.v, acc[0][1], 0, 0, 0);
    acc[1][1] = __builtin_amdgcn_mfma_f32_16x16x32_bf16(af1, b1.v, acc[1][1], 0, 0, 0);
    acc[0][2] = __builtin_amdgcn_mfma_f32_16x16x32_bf16(af0, b2.v, acc[0][2], 0, 0, 0);
    acc[1][2] = __builtin_amdgcn_mfma_f32_16x16x32_bf16(af1, b2.v, acc[1][2], 0, 0, 0);
    acc[0][3] = __builtin_amdgcn_mfma_f32_16x16x32_bf16(af0, b3.v, acc[0][3], 0, 0, 0);
    acc[1][3] = __builtin_amdgcn_mfma_f32_16x16x32_bf16(af1, b3.v, acc[1][3], 0, 0, 0);
  }

  __syncthreads();   // everyone done reading Pl; reuse it as the merge buffer
  merge_and_epilogue(acc, (f32x4*)Pl, wave, lane, fx, q, batch, rb,
                     bias, gamma, beta, out);
}

// ---- fallback (only if ws too small; correctness-only) ----
__global__ __launch_bounds__(512) void frp_fallback_kernel(
    const float* __restrict__ pos, const float* __restrict__ W,
    const float* __restrict__ bias, const float* __restrict__ gamma,
    const float* __restrict__ beta, float* __restrict__ out) {
  __shared__ f32x4 mbuf[4 * 512];
  const int tid = threadIdx.x;
  const int lane = tid & 63;
  const int wave = tid >> 6;
  const int fx = lane & 15;
  const int q = lane >> 4;
  const int batch = blockIdx.x >> 7;
  const int rb = (blockIdx.x & 127) * 32;
  const float* posB = pos + (size_t)batch * N_PTS * 3;

  f32x4 acc[2][4];
#pragma unroll
  for (int a = 0; a < 2; ++a)
#pragma unroll
    for (int t = 0; t < 4; ++t) acc[a][t] = (f32x4){0.f, 0.f, 0.f, 0.f};

  const int G0 = wave * 4 + q;
  const int n0 = rb + fx;
  const float px0 = posB[n0 * 3], py0 = posB[n0 * 3 + 1], pz0 = posB[n0 * 3 + 2];
  const float px1 = posB[(n0 + 16) * 3], py1 = posB[(n0 + 16) * 3 + 1],
              pz1 = posB[(n0 + 16) * 3 + 2];

  for (int c = 0; c < 16; ++c) {
    const int G = c * 32 + G0;
    bf16x8 af0, af1;
#pragma unroll
    for (int j = 0; j < 8; ++j) {
      const float* pk = posB + ((size_t)G * 8 + j) * 3;
      float kx = pk[0], ky = pk[1], kz = pk[2];
      float dx = kx - px0, dy = ky - py0, dz = kz - pz0;
      af0[j] = (__bf16)__builtin_amdgcn_sqrtf(dx * dx + dy * dy + dz * dz);
      dx = kx - px1; dy = ky - py1; dz = kz - pz1;
      af1[j] = (__bf16)__builtin_amdgcn_sqrtf(dx * dx + dy * dy + dz * dz);
    }
#pragma unroll
    for (int t = 0; t < 4; ++t) {
      const float* wr = W + (size_t)(t * 16 + fx) * N_PTS + G * 8;
      BF8 bw;
#pragma unroll
      for (int j = 0; j < 8; ++j) bw.v[j] = (__bf16)wr[j];
      acc[0][t] = __builtin_amdgcn_mfma_f32_16x16x32_bf16(af0, bw.v, acc[0][t], 0, 0, 0);
      acc[1][t] = __builtin_amdgcn_mfma_f32_16x16x32_bf16(af1, bw.v, acc[1][t], 0, 0, 0);
    }
  }
  merge_and_epilogue(acc, mbuf, wave, lane, fx, q, batch, rb,
                     bias, gamma, beta, out);
}

extern "C" void kernel_launch(void* const* d_in, const int* in_sizes, int n_in,
                              void* d_out, int out_size, void* d_ws, size_t ws_size,
                              hipStream_t stream) {
  const float* pos   = (const float*)d_in[0];  // (4,4096,3)
  const float* W     = (const float*)d_in[1];  // (64,4096)
  const float* bias  = (const float*)d_in[2];  // (64,)
  const float* gamma = (const float*)d_in[3];  // (64,)
  const float* beta  = (const float*)d_in[4];  // (64,)
  float* out = (float*)d_out;                  // (4,4096,64)

  const size_t wb_bytes = (size_t)FEATD * N_PTS * sizeof(unsigned short);  // 512 KiB
  const size_t pt_bytes = (size_t)3 * 4 * N_PTS * sizeof(float);           // 192 KiB
  int use_ws = (d_ws != nullptr && ws_size >= wb_bytes + pt_bytes);

  if (use_ws) {
    unsigned short* Wbt = (unsigned short*)d_ws;
    float* Pt = (float*)((char*)d_ws + wb_bytes);
    prep_kernel<<<dim3(144), dim3(256), 0, stream>>>(W, pos, Wbt, Pt);
    frp_kernel<<<dim3(512), dim3(512), 0, stream>>>(bias, gamma, beta, Wbt, Pt, out);
  } else {
    frp_fallback_kernel<<<dim3(512), dim3(512), 0, stream>>>(pos, W, bias, gamma,
                                                             beta, out);
  }
}